// Round 3
// baseline (706.680 us; speedup 1.0000x reference)
//
#include <hip/hip_runtime.h>

#define HH 192
#define WW 192
#define CC 128
#define BB 8
#define HW (HH * WW)          // 36864
#define OC 8
#define NPIX (BB * HW)        // 294912 elements per BN channel

typedef __attribute__((ext_vector_type(8))) short bf16x8;
typedef __attribute__((ext_vector_type(4))) float f32x4;

__device__ __forceinline__ unsigned short f2bf(float f) {
    unsigned int u = __float_as_uint(f);
    u += 0x7fffu + ((u >> 16) & 1u);          // RNE
    return (unsigned short)(u >> 16);
}

// ---------------------------------------------------------------------------
// T0: fp32 [b][c][h][w] -> bf16 [b][h][w][c] (c-contiguous for MFMA frags)
// ---------------------------------------------------------------------------
__global__ __launch_bounds__(256) void k_transpose(
    const float* __restrict__ x0, const float* __restrict__ x1,
    unsigned short* __restrict__ ws)
{
    const int h = blockIdx.x, b = blockIdx.y, t = blockIdx.z;
    const float* src = t ? x1 : x0;
    unsigned short* dst = ws + (size_t)t * ((size_t)BB * HH * WW * CC);
    __shared__ unsigned short lds[WW * 130];

    for (int idx = threadIdx.x; idx < CC * WW; idx += 256) {
        const int w = idx % WW, c = idx / WW;     // lanes: consecutive w -> coalesced
        const float v = src[((size_t)(b * CC + c) * HH + h) * WW + w];
        lds[w * 130 + c] = f2bf(v);
    }
    __syncthreads();
    unsigned int* dw = (unsigned int*)(dst + (size_t)(b * HH + h) * WW * CC);
    for (int idx = threadIdx.x; idx < WW * (CC / 2); idx += 256) {
        const int w = idx / (CC / 2), cp = idx % (CC / 2);  // lanes: consecutive cp
        const unsigned int lo = lds[w * 130 + 2 * cp];
        const unsigned int hi = lds[w * 130 + 2 * cp + 1];
        dw[w * (CC / 2) + cp] = lo | (hi << 16);
    }
}

// ---------------------------------------------------------------------------
// K1-MFMA v2: strip of 2 output rows (4 corr rows w/ halo), 768 blocks
// (3/CU), branchless clamped fragment loads masked at band extract, fp32
// corr LDS [4][194][11] (stride 11 words: coprime 32 banks).
// b = blockIdx.x & 7 clusters one batch image per XCD (L2 locality).
// ---------------------------------------------------------------------------
__global__ __launch_bounds__(384, 3) void k_corr_mfma_conv(
    const unsigned short* __restrict__ x0t, const unsigned short* __restrict__ x1t,
    const float* __restrict__ cw, const float* __restrict__ cb,
    float* __restrict__ y)
{
    const int bid  = blockIdx.x;
    const int b    = bid & 7;             // same-b -> same XCD (round-robin)
    const int i0   = (bid >> 3) * 2;
    const int tid  = threadIdx.x;
    const int wave = tid >> 6, lane = tid & 63;
    const int ln15 = lane & 15, kg = lane >> 4;

    __shared__ float corr[4][194][11];    // jj = col+1; cols 0,193 stay zero

    if (tid < 88) {                        // zero the pad columns once
        const int ir = tid / 22, rem = tid % 22;
        const int pj = rem % 11, jj = (rem < 11) ? 0 : 193;
        corr[ir][jj][pj] = 0.f;
    }

    float yacc[OC];
#pragma unroll
    for (int o = 0; o < OC; ++o) yacc[o] = 0.f;

    const int oi = tid / 192;             // 0..1: output row within strip
    const int jt = tid % 192;             // output column

    for (int pi = 0; pi < 11; ++pi) {
        __syncthreads();                  // conv(pi-1) done reading corr

        // ---------------- MFMA band-GEMM phase: 48 groups ----------------
        for (int g = wave; g < 48; g += 6) {
            const int ir  = g / 12, rem = g % 12;
            const int par = rem / 6, ut = rem % 6;
            const int u0  = ut * 16;
            const int i   = i0 - 1 + ir;
            const int r   = i + 2 * pi - 10;
            const bool gv = (i >= 0) && (i < HH) && (r >= 0) && (r < HH);
            const int icl = min(max(i, 0), HH - 1);
            const int rcl = min(max(r, 0), HH - 1);

            // A: row u = u0+ln15 (always in range), k = c in [kg*8, +8)
            const unsigned short* pa =
                x0t + ((size_t)((b * HH + icl) * WW + (2 * (u0 + ln15) + par)) * CC + kg * 8);
            const bf16x8 a0 = *(const bf16x8*)(pa);
            const bf16x8 a1 = *(const bf16x8*)(pa + 32);
            const bf16x8 a2 = *(const bf16x8*)(pa + 64);
            const bf16x8 a3 = *(const bf16x8*)(pa + 96);

#pragma unroll
            for (int vt = 0; vt < 2; ++vt) {
                const int v0  = u0 - 8 + vt * 16;
                const int v   = v0 + ln15;
                const int vcl = min(max(v, 0), 95);
                const unsigned short* pb =
                    x1t + ((size_t)((b * HH + rcl) * WW + (2 * vcl + par)) * CC + kg * 8);
                const bf16x8 b0 = *(const bf16x8*)(pb);
                const bf16x8 b1 = *(const bf16x8*)(pb + 32);
                const bf16x8 b2 = *(const bf16x8*)(pb + 64);
                const bf16x8 b3 = *(const bf16x8*)(pb + 96);

                f32x4 c = {0.f, 0.f, 0.f, 0.f};
                c = __builtin_amdgcn_mfma_f32_16x16x32_bf16(a0, b0, c, 0, 0, 0);
                c = __builtin_amdgcn_mfma_f32_16x16x32_bf16(a1, b1, c, 0, 0, 0);
                c = __builtin_amdgcn_mfma_f32_16x16x32_bf16(a2, b2, c, 0, 0, 0);
                c = __builtin_amdgcn_mfma_f32_16x16x32_bf16(a3, b3, c, 0, 0, 0);

                const bool lv = gv && (v >= 0) && (v < 96);   // mask garbage here
#pragma unroll
                for (int reg = 0; reg < 4; ++reg) {
                    const int u  = u0 + kg * 4 + reg;
                    const int pj = v - u + 5;
                    if (pj >= 0 && pj < 11)
                        corr[ir][2 * u + par + 1][pj] = lv ? c[reg] : 0.f;
                }
            }
        }
        __syncthreads();                  // corr slice visible

        // ---------------- conv(3x3, 121->8) VALU phase, 1 px/thread -------
        for (int ki = 0; ki < 3; ++ki) {
            for (int kj = 0; kj < 3; ++kj) {
                const float* cp = &corr[oi + ki][jt + kj][0];
                float cv[11];
#pragma unroll
                for (int pj = 0; pj < 11; ++pj) cv[pj] = cp[pj];
#pragma unroll
                for (int o = 0; o < OC; ++o) {
                    float acc = yacc[o];
#pragma unroll
                    for (int pj = 0; pj < 11; ++pj) {
                        const float wv =              // wave-uniform -> s_load
                            cw[(((o * 121) + pi * 11 + pj) * 3 + ki) * 3 + kj];
                        acc = fmaf(wv, cv[pj], acc);
                    }
                    yacc[o] = acc;
                }
            }
        }
    }

    const int irow = i0 + oi;
#pragma unroll
    for (int o = 0; o < OC; ++o)
        y[((size_t)(b * OC + o) * HH + irow) * WW + jt] = yacc[o] + cb[o];
}

// ---------------------------------------------------------------------------
// Fallback K1 (round-1 verified fp32 path) — only if ws too small
// ---------------------------------------------------------------------------
__global__ __launch_bounds__(256) void k_corr_conv(
    const float* __restrict__ x0, const float* __restrict__ x1,
    const float* __restrict__ cw, const float* __restrict__ cb,
    float* __restrict__ y)
{
    const int b  = blockIdx.z;
    const int i0 = blockIdx.y * 14;
    const int j0 = blockIdx.x * 14;
    const int li = threadIdx.x >> 4;
    const int lj = threadIdx.x & 15;
    const int gi = i0 + li - 1;
    const int gj = j0 + lj - 1;
    const bool valid    = (gi >= 0) & (gi < HH) & (gj >= 0) & (gj < WW);
    const bool interior = (li >= 1) & (li <= 14) & (lj >= 1) & (lj <= 14)
                        & (gi < HH) & (gj < WW);

    __shared__ float corr[16][16][13];

    float yacc[OC];
#pragma unroll
    for (int o = 0; o < OC; ++o) yacc[o] = 0.f;

    const size_t bbase = (size_t)b * CC * HW;
    const float* x0p = x0 + bbase + (size_t)gi * WW + gj;

    for (int pi = 0; pi < 11; ++pi) {
        float acc[11];
#pragma unroll
        for (int k = 0; k < 11; ++k) acc[k] = 0.f;

        const int r = gi + 2 * pi - 10;
        if (valid && r >= 0 && r < HH) {
            const float* p0 = x0p;
            if (gj >= 10 && gj <= WW - 11) {
                const float* p1o = x1 + bbase + (size_t)r * WW + (gj - 10);
#pragma unroll 2
                for (int c = 0; c < CC; ++c) {
                    const float a = *p0;
#pragma unroll
                    for (int k = 0; k < 11; ++k)
                        acc[k] = fmaf(a, p1o[2 * k], acc[k]);
                    p0 += HW; p1o += HW;
                }
            } else {
                const float* p1 = x1 + bbase + (size_t)r * WW;
#pragma unroll 2
                for (int c = 0; c < CC; ++c) {
                    const float a = *p0;
#pragma unroll
                    for (int k = 0; k < 11; ++k) {
                        const int col = gj + 2 * k - 10;
                        const float v = (col >= 0 && col < WW) ? p1[col] : 0.f;
                        acc[k] = fmaf(a, v, acc[k]);
                    }
                    p0 += HW; p1 += HW;
                }
            }
        }

        __syncthreads();
#pragma unroll
        for (int k = 0; k < 11; ++k) corr[li][lj][k] = acc[k];
        __syncthreads();

        if (interior) {
#pragma unroll
            for (int ki = 0; ki < 3; ++ki) {
#pragma unroll
                for (int kj = 0; kj < 3; ++kj) {
                    float cv[11];
#pragma unroll
                    for (int k = 0; k < 11; ++k)
                        cv[k] = corr[li + ki - 1][lj + kj - 1][k];
#pragma unroll
                    for (int o = 0; o < OC; ++o) {
#pragma unroll
                        for (int k = 0; k < 11; ++k) {
                            const float wv =
                                cw[(((o * 121) + pi * 11 + k) * 3 + ki) * 3 + kj];
                            yacc[o] = fmaf(wv, cv[k], yacc[o]);
                        }
                    }
                }
            }
        }
    }

    if (interior) {
#pragma unroll
        for (int o = 0; o < OC; ++o)
            y[(size_t)(b * OC + o) * HW + (size_t)gi * WW + gj] = yacc[o] + cb[o];
    }
}

// ---------------------------------------------------------------------------
// BN stats + apply (unchanged)
// ---------------------------------------------------------------------------
__global__ __launch_bounds__(256) void k_stats_partial(
    const float* __restrict__ y, float* __restrict__ ws)
{
    const int o = blockIdx.x & 7;
    const int b = blockIdx.x >> 3;
    const float4* p = (const float4*)(y + (size_t)(b * OC + o) * HW);
    float s = 0.f, q = 0.f;
    for (int t = threadIdx.x; t < HW / 4; t += 256) {
        const float4 v = p[t];
        s += v.x + v.y + v.z + v.w;
        q = fmaf(v.x, v.x, q); q = fmaf(v.y, v.y, q);
        q = fmaf(v.z, v.z, q); q = fmaf(v.w, v.w, q);
    }
#pragma unroll
    for (int off = 32; off > 0; off >>= 1) {
        s += __shfl_down(s, off);
        q += __shfl_down(q, off);
    }
    __shared__ float ss[4], sq[4];
    const int lane = threadIdx.x & 63, wv = threadIdx.x >> 6;
    if (lane == 0) { ss[wv] = s; sq[wv] = q; }
    __syncthreads();
    if (threadIdx.x == 0) {
        ws[blockIdx.x]      = ss[0] + ss[1] + ss[2] + ss[3];
        ws[64 + blockIdx.x] = sq[0] + sq[1] + sq[2] + sq[3];
    }
}

__global__ void k_stats_final(float* __restrict__ ws,
                              const float* __restrict__ gamma,
                              const float* __restrict__ beta)
{
    const int o = threadIdx.x;
    if (o < 8) {
        float S = 0.f, Q = 0.f;
#pragma unroll
        for (int b = 0; b < 8; ++b) {
            S += ws[b * 8 + o];
            Q += ws[64 + b * 8 + o];
        }
        const float invN = 1.f / (float)NPIX;
        const float mean = S * invN;
        const float var  = Q * invN - mean * mean;
        const float sc   = gamma[o] / sqrtf(var + 1e-5f);
        ws[128 + o] = sc;
        ws[136 + o] = beta[o] - mean * sc;
    }
}

__global__ __launch_bounds__(256) void k_bn_relu(
    float* __restrict__ y, const float* __restrict__ ws)
{
    const int i = blockIdx.x * 256 + threadIdx.x;
    const int o = (i / (HW / 4)) & 7;
    const float sc = ws[128 + o], sh = ws[136 + o];
    float4 v = ((float4*)y)[i];
    v.x = fmaxf(fmaf(v.x, sc, sh), 0.f);
    v.y = fmaxf(fmaf(v.y, sc, sh), 0.f);
    v.z = fmaxf(fmaf(v.z, sc, sh), 0.f);
    v.w = fmaxf(fmaf(v.w, sc, sh), 0.f);
    ((float4*)y)[i] = v;
}

extern "C" void kernel_launch(void* const* d_in, const int* in_sizes, int n_in,
                              void* d_out, int out_size, void* d_ws, size_t ws_size,
                              hipStream_t stream)
{
    const float* x0    = (const float*)d_in[0];
    const float* x1    = (const float*)d_in[1];
    const float* cw    = (const float*)d_in[2];
    const float* cb    = (const float*)d_in[3];
    const float* gamma = (const float*)d_in[4];
    const float* beta  = (const float*)d_in[5];
    float* y  = (float*)d_out;
    float* ws = (float*)d_ws;

    const size_t need = (size_t)2 * BB * HH * WW * CC * sizeof(unsigned short); // 151 MB

    if (ws_size >= need) {
        unsigned short* x0t = (unsigned short*)d_ws;
        unsigned short* x1t = x0t + (size_t)BB * HH * WW * CC;
        k_transpose<<<dim3(HH, BB, 2), 256, 0, stream>>>(x0, x1, (unsigned short*)d_ws);
        k_corr_mfma_conv<<<768, 384, 0, stream>>>(x0t, x1t, cw, cb, y);
    } else {
        dim3 g1(14, 14, 8);
        k_corr_conv<<<g1, 256, 0, stream>>>(x0, x1, cw, cb, y);
    }
    k_stats_partial<<<64, 256, 0, stream>>>(y, ws);
    k_stats_final<<<1, 64, 0, stream>>>(ws, gamma, beta);
    k_bn_relu<<<(OC * BB * HW / 4) / 256, 256, 0, stream>>>(y, ws);
}